// Round 5
// baseline (14487.134 us; speedup 1.0000x reference)
//
#include <hip/hip_runtime.h>

#define T_STEPS 512
#define BATCH   128
#define IND     300
#define KP      320   // K padded to 10*32 for MFMA
#define MEM     512
#define NWG     64    // workgroups in the persistent scan kernel

typedef short bf16x8 __attribute__((ext_vector_type(8)));
typedef float f32x4  __attribute__((ext_vector_type(4)));
typedef unsigned short u16x4 __attribute__((ext_vector_type(4)));

__device__ __forceinline__ unsigned short f2bf(float f){
  unsigned u = __float_as_uint(f);
  u += 0x7FFFu + ((u >> 16) & 1u);           // RNE
  return (unsigned short)(u >> 16);
}
__device__ __forceinline__ float bf2f(unsigned short s){
  return __uint_as_float(((unsigned)s) << 16);
}
__device__ __forceinline__ f32x4 mfma16(bf16x8 a, bf16x8 b, f32x4 c){
  return __builtin_amdgcn_mfma_f32_16x16x32_bf16(a, b, c, 0, 0, 0);
}
__device__ __forceinline__ float sigm(float x){ return 1.0f/(1.0f + __expf(-x)); }
__device__ __forceinline__ float tanh_(float x){
  float t = __expf(-2.0f * fabsf(x));
  float r = (1.0f - t)/(1.0f + t);
  return x < 0.0f ? -r : r;
}

// ---- MALL-coherent (write-through / uncached) scalar ops ----
__device__ __forceinline__ void st8_sc(void* p, unsigned long long v){
  __hip_atomic_store((unsigned long long*)p, v, __ATOMIC_RELAXED,
                     __HIP_MEMORY_SCOPE_SYSTEM);
}
__device__ __forceinline__ void st4_sc(unsigned* p, unsigned v){
  __hip_atomic_store(p, v, __ATOMIC_RELAXED, __HIP_MEMORY_SCOPE_SYSTEM);
}
__device__ __forceinline__ unsigned ld4_sc(const unsigned* p){
  return __hip_atomic_load(p, __ATOMIC_RELAXED, __HIP_MEMORY_SCOPE_SYSTEM);
}
// agent-scope acquire: compiler emits load + s_waitcnt + buffer_inv (L1+L2 flash
// invalidate). Invalidate-clean is cheap; all scan stores are write-through so
// the L2 never holds dirty scan data when this runs.
__device__ __forceinline__ unsigned ld4_acq_agent(const unsigned* p){
  return __hip_atomic_load(p, __ATOMIC_ACQUIRE, __HIP_MEMORY_SCOPE_AGENT);
}

// ---- batched CACHED loads: 32 x global_load_dwordx4 (L2-served) from one base ----
// Row layout: [128][1024] ushort, row = hi[0..511] ++ lo[0..511]; all 32
// fragments within imm offsets 0..1984 of (row base + lk).
#define G16(i, ofs) "global_load_dwordx4 %" #i ", %16, off offset:" #ofs "\n\t"
__device__ __forceinline__ void ld_row_batch(const unsigned short* p,
                                             bf16x8* A, bf16x8* B){
  asm volatile(
    G16(0,0)    G16(1,64)   G16(2,128)  G16(3,192)
    G16(4,256)  G16(5,320)  G16(6,384)  G16(7,448)
    G16(8,512)  G16(9,576)  G16(10,640) G16(11,704)
    G16(12,768) G16(13,832) G16(14,896) G16(15,960)
    : "=&v"(A[0]),"=&v"(A[1]),"=&v"(A[2]),"=&v"(A[3]),
      "=&v"(A[4]),"=&v"(A[5]),"=&v"(A[6]),"=&v"(A[7]),
      "=&v"(A[8]),"=&v"(A[9]),"=&v"(A[10]),"=&v"(A[11]),
      "=&v"(A[12]),"=&v"(A[13]),"=&v"(A[14]),"=&v"(A[15])
    : "v"(p));
  asm volatile(
    G16(0,1024) G16(1,1088) G16(2,1152) G16(3,1216)
    G16(4,1280) G16(5,1344) G16(6,1408) G16(7,1472)
    G16(8,1536) G16(9,1600) G16(10,1664) G16(11,1728)
    G16(12,1792) G16(13,1856) G16(14,1920) G16(15,1984)
    : "=&v"(B[0]),"=&v"(B[1]),"=&v"(B[2]),"=&v"(B[3]),
      "=&v"(B[4]),"=&v"(B[5]),"=&v"(B[6]),"=&v"(B[7]),
      "=&v"(B[8]),"=&v"(B[9]),"=&v"(B[10]),"=&v"(B[11]),
      "=&v"(B[12]),"=&v"(B[13]),"=&v"(B[14]),"=&v"(B[15])
    : "v"(p));
}

// ---- x fp32 [T,B,300] -> bf16 hi/lo planes [T,B,320] ----
__global__ __launch_bounds__(256) void prep_x(const float* __restrict__ x,
                                              unsigned short* __restrict__ xh,
                                              unsigned short* __restrict__ xl){
  long long n = (long long)T_STEPS * BATCH * KP;
  for (long long i = (long long)blockIdx.x * blockDim.x + threadIdx.x; i < n;
       i += (long long)gridDim.x * blockDim.x){
    int k = (int)(i % KP);
    long long tb = i / KP;
    float v = (k < IND) ? x[tb * IND + k] : 0.0f;
    unsigned short h = f2bf(v);
    xh[i] = h;
    xl[i] = f2bf(v - bf2f(h));
  }
}

// ---- one-shot W_ioux/W_fx fp32 -> bf16 hi/lo [1536][320] ----
__global__ __launch_bounds__(256) void prep_w(const float* __restrict__ Wioux,
                                              const float* __restrict__ Wfx,
                                              unsigned short* __restrict__ wxh,
                                              unsigned short* __restrict__ wxl){
  int n = 1536 * KP;
  for (int i = blockIdx.x * blockDim.x + threadIdx.x; i < n;
       i += gridDim.x * blockDim.x){
    int k = i % KP, row = i / KP;
    float v = 0.0f;
    if (k < IND) v = (row < 1024) ? Wioux[row*IND + k] : Wfx[(row-1024)*IND + k];
    unsigned short h = f2bf(v);
    wxh[i] = h;
    wxl[i] = f2bf(v - bf2f(h));
  }
}

// ---- P_iou[t][o][b] = x_t[b,:]·W_ioux[o,:] + b_ioux[o] + b_iouh[o] ----
__global__ __launch_bounds__(256) void proj_iou(const unsigned short* __restrict__ xh,
                                                const unsigned short* __restrict__ xl,
                                                const unsigned short* __restrict__ wxh,
                                                const unsigned short* __restrict__ wxl,
                                                const float* __restrict__ bx,
                                                const float* __restrict__ bh,
                                                float* __restrict__ P){
  const int t = blockIdx.x, obase = blockIdx.y * 64;
  __shared__ unsigned short wh[64*328];
  __shared__ unsigned short wl[64*328];
  for (int c = threadIdx.x; c < 64*40; c += 256){
    int r = c / 40, c8 = (c % 40) * 8;
    *(bf16x8*)(wh + r*328 + c8) = *(const bf16x8*)(wxh + (obase + r)*KP + c8);
    *(bf16x8*)(wl + r*328 + c8) = *(const bf16x8*)(wxl + (obase + r)*KP + c8);
  }
  __syncthreads();
  const int lane = threadIdx.x & 63, w = threadIdx.x >> 6;
  const int l15 = lane & 15, lk = (lane >> 4) << 3, lr4 = (lane >> 4) << 2;
  f32x4 acc[2][4] = {};
  const unsigned short* xbh = xh + (long long)t * BATCH * KP;
  const unsigned short* xbl = xl + (long long)t * BATCH * KP;
  for (int ks = 0; ks < 10; ++ks){
    int k0 = ks*32 + lk;
    bf16x8 ah[2], al[2];
    #pragma unroll
    for (int mt = 0; mt < 2; ++mt){
      int b = w*32 + mt*16 + l15;
      ah[mt] = *(const bf16x8*)(xbh + b*KP + k0);
      al[mt] = *(const bf16x8*)(xbl + b*KP + k0);
    }
    #pragma unroll
    for (int nt = 0; nt < 4; ++nt){
      bf16x8 bh8 = *(const bf16x8*)(wh + (nt*16 + l15)*328 + k0);
      bf16x8 bl8 = *(const bf16x8*)(wl + (nt*16 + l15)*328 + k0);
      #pragma unroll
      for (int mt = 0; mt < 2; ++mt){
        acc[mt][nt] = mfma16(ah[mt], bh8, acc[mt][nt]);
        acc[mt][nt] = mfma16(ah[mt], bl8, acc[mt][nt]);
        acc[mt][nt] = mfma16(al[mt], bh8, acc[mt][nt]);
      }
    }
  }
  #pragma unroll
  for (int nt = 0; nt < 4; ++nt){
    int o = obase + nt*16 + l15;
    float bias = bx[o] + bh[o];
    #pragma unroll
    for (int mt = 0; mt < 2; ++mt){
      int b0 = w*32 + mt*16 + lr4;
      *(f32x4*)(P + ((long long)t*1024 + o)*BATCH + b0) = acc[mt][nt] + bias;
    }
  }
}

// ---- P_f[t][b][m] = x_t[b,:]·W_fx[m,:] + b_fx[m] + b_Uh[m] ----
__global__ __launch_bounds__(256) void proj_f(const unsigned short* __restrict__ xh,
                                              const unsigned short* __restrict__ xl,
                                              const unsigned short* __restrict__ wxh,
                                              const unsigned short* __restrict__ wxl,
                                              const float* __restrict__ bf,
                                              const float* __restrict__ bu,
                                              float* __restrict__ Pf){
  const int t = blockIdx.x, mbase = blockIdx.y * 64;
  __shared__ unsigned short wh[64*328];
  __shared__ unsigned short wl[64*328];
  for (int c = threadIdx.x; c < 64*40; c += 256){
    int r = c / 40, c8 = (c % 40) * 8;
    *(bf16x8*)(wh + r*328 + c8) = *(const bf16x8*)(wxh + (1024 + mbase + r)*KP + c8);
    *(bf16x8*)(wl + r*328 + c8) = *(const bf16x8*)(wxl + (1024 + mbase + r)*KP + c8);
  }
  __syncthreads();
  const int lane = threadIdx.x & 63, w = threadIdx.x >> 6;
  const int l15 = lane & 15, lk = (lane >> 4) << 3, lr4 = (lane >> 4) << 2;
  f32x4 acc[4][2] = {};
  const unsigned short* xbh = xh + (long long)t * BATCH * KP;
  const unsigned short* xbl = xl + (long long)t * BATCH * KP;
  for (int ks = 0; ks < 10; ++ks){
    int k0 = ks*32 + lk;
    bf16x8 bh8[2], bl8[2];
    #pragma unroll
    for (int nt = 0; nt < 2; ++nt){
      int b = w*32 + nt*16 + l15;
      bh8[nt] = *(const bf16x8*)(xbh + b*KP + k0);
      bl8[nt] = *(const bf16x8*)(xbl + b*KP + k0);
    }
    #pragma unroll
    for (int mt = 0; mt < 4; ++mt){
      bf16x8 ah = *(const bf16x8*)(wh + (mt*16 + l15)*328 + k0);
      bf16x8 al = *(const bf16x8*)(wl + (mt*16 + l15)*328 + k0);
      #pragma unroll
      for (int nt = 0; nt < 2; ++nt){
        acc[mt][nt] = mfma16(ah, bh8[nt], acc[mt][nt]);
        acc[mt][nt] = mfma16(ah, bl8[nt], acc[mt][nt]);
        acc[mt][nt] = mfma16(al, bh8[nt], acc[mt][nt]);
      }
    }
  }
  #pragma unroll
  for (int mt = 0; mt < 4; ++mt){
    int m0 = mbase + mt*16 + lr4;
    f32x4 bias = *(const f32x4*)(bf + m0);
    f32x4 bias2 = *(const f32x4*)(bu + m0);
    #pragma unroll
    for (int nt = 0; nt < 2; ++nt){
      int b = w*32 + nt*16 + l15;
      *(f32x4*)(Pf + ((long long)t*BATCH + b)*MEM + m0) = acc[mt][nt] + bias + bias2;
    }
  }
}

// ---- persistent GRU scan: 64 WGs x 512 threads ----
// Producers: write-through sc0 sc1 stores (MALL = coherence point; L2 never dirty).
// Consumers: per-phase agent-acquire (flash L1+L2 invalidate) then CACHED batch
// loads -> each XCD fetches h/rh from MALL once, 8 WGs share it via L2.
__global__ __launch_bounds__(512, 2) void scan_kernel(
    const float* __restrict__ Wiouh, const float* __restrict__ Wuh,
    const float* __restrict__ Piou, const float* __restrict__ Pf,
    unsigned short* __restrict__ h2, unsigned short* __restrict__ rh2,
    float* __restrict__ out, unsigned* __restrict__ slots)
{
  const int g = blockIdx.x;
  const int tid = threadIdx.x;
  const int lane = tid & 63, w = tid >> 6;
  const int l15 = lane & 15, lk = (lane >> 4) << 3, lr4 = (lane >> 4) << 2;

  __shared__ unsigned short zr_h[16*520];   // rows 0-7: W_iouh z-slice, 8-15: r-slice
  __shared__ unsigned short zr_l[16*520];
  __shared__ unsigned short wu_h[16*520];   // rows 0-7: W_Uh slice, 8-15: zeros
  __shared__ unsigned short wu_l[16*520];
  __shared__ float          z_lds[BATCH*8];
  __shared__ unsigned short fl_h[BATCH*8];
  __shared__ unsigned short fl_l[BATCH*8];
  __shared__ float          hn_lds[8*BATCH];

  for (int idx = tid; idx < 16*512; idx += 512){
    int r = idx >> 9, k = idx & 511;
    float vz = (r < 8) ? Wiouh[(g*8 + r)*512 + k]
                       : Wiouh[(512 + g*8 + (r - 8))*512 + k];
    unsigned short hz = f2bf(vz);
    zr_h[r*520 + k] = hz;
    zr_l[r*520 + k] = f2bf(vz - bf2f(hz));
    float vu = (r < 8) ? Wuh[(g*8 + r)*512 + k] : 0.0f;
    unsigned short hu = f2bf(vu);
    wu_h[r*520 + k] = hu;
    wu_l[r*520 + k] = f2bf(vu - bf2f(hu));
  }
  for (int idx = tid; idx < 8*BATCH; idx += 512) hn_lds[idx] = 0.0f;
  __syncthreads();

  const bool is_z = (l15 < 8);
  const int o_p = is_z ? (g*8 + l15) : (512 + g*8 + (l15 - 8)); // P_iou row
  const bool valid2 = (lane >> 4) < 2;
  const int b0 = w*16 + lr4;
  const int b2 = w*16 + l15;          // batch row for A(phase1) / B(phase2)
  const int m0g = g*8 + lr4;
  const unsigned short* ph = h2  + b2*1024 + lk;
  const unsigned short* pr = rh2 + b2*1024 + lk;
  unsigned gen = 0;

  f32x4 p1 = *(const f32x4*)(Piou + (long long)o_p*BATCH + b0);  // t = 0

  for (int t = 0; t < T_STEPS; ++t){
    // ================= phase 1: iou = h @ W_zr^T =================
    {
      bf16x8 Ah[16], Al[16];
      __builtin_amdgcn_sched_barrier(0);
      ld_row_batch(ph, Ah, Al);
      asm volatile("s_waitcnt vmcnt(0)" ::: "memory");
      __builtin_amdgcn_sched_barrier(0);
      f32x4 acc1 = {0.f,0.f,0.f,0.f};
      #pragma unroll
      for (int ks = 0; ks < 16; ++ks){
        int k0 = ks*32 + lk;
        bf16x8 b_h = *(const bf16x8*)(zr_h + l15*520 + k0);
        bf16x8 b_l = *(const bf16x8*)(zr_l + l15*520 + k0);
        acc1 = mfma16(Ah[ks], b_h, acc1);
        acc1 = mfma16(Ah[ks], b_l, acc1);
        acc1 = mfma16(Al[ks], b_h, acc1);
      }
      if (is_z){
        #pragma unroll
        for (int j = 0; j < 4; ++j){
          float zv = sigm(acc1[j] + p1[j]);
          z_lds[(b0 + j)*8 + l15] = zv;
        }
      } else {
        #pragma unroll
        for (int j = 0; j < 4; ++j){
          float rv = sigm(acc1[j] + p1[j]);
          float rh = rv * hn_lds[(l15 - 8)*BATCH + b0 + j];
          unsigned short hi = f2bf(rh);
          fl_h[(b0 + j)*8 + (l15 - 8)] = hi;
          fl_l[(b0 + j)*8 + (l15 - 8)] = f2bf(rh - bf2f(hi));
        }
      }
    }
    __syncthreads();
    { // flush rh slice write-through to MALL: 512 threads x 8B
      int b = tid >> 2, q = tid & 3;
      int plane = q >> 1, half = q & 1;
      const unsigned short* src = (plane ? fl_l : fl_h) + b*8 + half*4;
      unsigned long long v = *(const unsigned long long*)src;
      st8_sc(rh2 + b*1024 + plane*512 + g*8 + half*4, v);
    }
    __syncthreads();                     // per-wave vmcnt(0) drain before s_barrier
    ++gen;
    if (tid == 0) st4_sc(&slots[g], gen);
    f32x4 p2 = {0.f,0.f,0.f,0.f};
    if (valid2) p2 = *(const f32x4*)(Pf + ((long long)t*BATCH + b2)*MEM + m0g);
    if (tid < 64){
      for (;;){
        unsigned v = ld4_sc(&slots[tid]);
        if (__all((int)(v >= gen))) break;
        __builtin_amdgcn_s_sleep(2);
      }
    }
    __syncthreads();
    (void)ld4_acq_agent(&slots[g]);      // flash-invalidate L1+L2 (clean) this phase
    __builtin_amdgcn_sched_barrier(0);

    // ================= phase 2: u = rh @ W_U^T =================
    {
      bf16x8 Bh[16], Bl[16];
      __builtin_amdgcn_sched_barrier(0);
      ld_row_batch(pr, Bh, Bl);
      asm volatile("s_waitcnt vmcnt(0)" ::: "memory");
      __builtin_amdgcn_sched_barrier(0);
      f32x4 acc2 = {0.f,0.f,0.f,0.f};
      #pragma unroll
      for (int ks = 0; ks < 16; ++ks){
        int k0 = ks*32 + lk;
        bf16x8 a_h = *(const bf16x8*)(wu_h + l15*520 + k0);
        bf16x8 a_l = *(const bf16x8*)(wu_l + l15*520 + k0);
        acc2 = mfma16(a_h, Bh[ks], acc2);
        acc2 = mfma16(a_h, Bl[ks], acc2);
        acc2 = mfma16(a_l, Bh[ks], acc2);
      }
      if (valid2){
        f32x4 zz = *(const f32x4*)(&z_lds[b2*8 + lr4]);
        f32x4 hn;
        u16x4 nh, nl;
        #pragma unroll
        for (int j = 0; j < 4; ++j){
          float h_old = hn_lds[(lr4 + j)*BATCH + b2];
          float ht = tanh_(acc2[j] + p2[j]);
          float hv = (1.0f - zz[j])*h_old + zz[j]*ht;
          hn[j] = hv;
          unsigned short nhi = f2bf(hv);
          nh[j] = nhi;
          nl[j] = f2bf(hv - bf2f(nhi));
          hn_lds[(lr4 + j)*BATCH + b2] = hv;
        }
        // out must be write-through too: L2 may never hold dirty scan data,
        // since the per-phase flash invalidate discards without writeback.
        float* outp = out + ((long long)t*BATCH + b2)*MEM + m0g;
        union { f32x4 v; unsigned long long q[2]; } uo; uo.v = hn;
        st8_sc(outp, uo.q[0]);
        st8_sc(outp + 2, uo.q[1]);
        union { u16x4 s; unsigned long long q; } uh, ul;
        uh.s = nh; ul.s = nl;
        st8_sc(h2 + b2*1024 + m0g, uh.q);          // hi plane
        st8_sc(h2 + b2*1024 + 512 + m0g, ul.q);    // lo plane
      }
    }
    __syncthreads();                     // drain h/out stores
    ++gen;
    if (tid == 0) st4_sc(&slots[g], gen);
    if (t + 1 < T_STEPS)
      p1 = *(const f32x4*)(Piou + ((long long)(t+1)*1024 + o_p)*BATCH + b0);
    if (tid < 64){
      for (;;){
        unsigned v = ld4_sc(&slots[tid]);
        if (__all((int)(v >= gen))) break;
        __builtin_amdgcn_s_sleep(2);
      }
    }
    __syncthreads();
    (void)ld4_acq_agent(&slots[g]);      // flash-invalidate before next phase-1 reads
    __builtin_amdgcn_sched_barrier(0);
  }
}

extern "C" void kernel_launch(void* const* d_in, const int* in_sizes, int n_in,
                              void* d_out, int out_size, void* d_ws, size_t ws_size,
                              hipStream_t stream){
  (void)in_sizes; (void)n_in; (void)out_size; (void)ws_size;
  const float* x     = (const float*)d_in[0];
  const float* Wioux = (const float*)d_in[1];
  const float* bioux = (const float*)d_in[2];
  const float* Wiouh = (const float*)d_in[3];
  const float* biouh = (const float*)d_in[4];
  const float* Wfx   = (const float*)d_in[5];
  const float* bfx   = (const float*)d_in[6];
  const float* Wuh   = (const float*)d_in[7];
  const float* buh   = (const float*)d_in[8];
  float* out = (float*)d_out;

  char* ws = (char*)d_ws;
  size_t off = 0;
  auto alloc = [&](size_t bytes) -> void* {
    void* p = ws + off;
    off += (bytes + 255) & ~(size_t)255;
    return p;
  };
  float* Piou = (float*)alloc((size_t)T_STEPS*1024*BATCH*sizeof(float)); // 268 MB
  float* Pf   = (float*)alloc((size_t)T_STEPS*BATCH*MEM*sizeof(float));  // 134 MB
  unsigned short* xh = (unsigned short*)alloc((size_t)T_STEPS*BATCH*KP*2);
  unsigned short* xl = (unsigned short*)alloc((size_t)T_STEPS*BATCH*KP*2);
  unsigned short* wxh = (unsigned short*)alloc((size_t)1536*KP*2);
  unsigned short* wxl = (unsigned short*)alloc((size_t)1536*KP*2);
  unsigned short* h2  = (unsigned short*)alloc((size_t)BATCH*1024*2);
  unsigned short* rh2 = (unsigned short*)alloc((size_t)BATCH*1024*2);
  unsigned* slots = (unsigned*)alloc(256);

  hipMemsetAsync(h2, 0, (size_t)BATCH*1024*2, stream);   // h0 = 0
  hipMemsetAsync(slots, 0, 256, stream);                 // barrier slots

  prep_x<<<2048, 256, 0, stream>>>(x, xh, xl);
  prep_w<<<512, 256, 0, stream>>>(Wioux, Wfx, wxh, wxl);
  proj_iou<<<dim3(T_STEPS, 16), 256, 0, stream>>>(xh, xl, wxh, wxl, bioux, biouh, Piou);
  proj_f<<<dim3(T_STEPS, 8), 256, 0, stream>>>(xh, xl, wxh, wxl, bfx, buh, Pf);
  scan_kernel<<<NWG, 512, 0, stream>>>(Wiouh, Wuh, Piou, Pf, h2, rh2, out, slots);
}

// Round 7
// 6666.681 us; speedup vs baseline: 2.1731x; 2.1731x over previous
//
#include <hip/hip_runtime.h>

#define T_STEPS 512
#define BATCH   128
#define IND     300
#define KP      320   // K padded to 10*32 for MFMA
#define MEM     512
#define NWG     256   // 8 batch-groups x 32 col-groups, 1 wave each

typedef short bf16x8 __attribute__((ext_vector_type(8)));
typedef float f32x4  __attribute__((ext_vector_type(4)));
typedef unsigned short u16x4 __attribute__((ext_vector_type(4)));
typedef unsigned int u32x4 __attribute__((ext_vector_type(4)));

__device__ __forceinline__ unsigned short f2bf(float f){
  unsigned u = __float_as_uint(f);
  u += 0x7FFFu + ((u >> 16) & 1u);           // RNE
  return (unsigned short)(u >> 16);
}
__device__ __forceinline__ float bf2f(unsigned short s){
  return __uint_as_float(((unsigned)s) << 16);
}
__device__ __forceinline__ f32x4 mfma16(bf16x8 a, bf16x8 b, f32x4 c){
  return __builtin_amdgcn_mfma_f32_16x16x32_bf16(a, b, c, 0, 0, 0);
}
__device__ __forceinline__ float sigm(float x){ return 1.0f/(1.0f + __expf(-x)); }
__device__ __forceinline__ float tanh_(float x){
  float t = __expf(-2.0f * fabsf(x));
  float r = (1.0f - t)/(1.0f + t);
  return x < 0.0f ? -r : r;
}

// ---- MALL-coherent (write-through / uncached) ops — round-2/4-verified path ----
__device__ __forceinline__ void st8_sc(void* p, unsigned long long v){
  __hip_atomic_store((unsigned long long*)p, v, __ATOMIC_RELAXED,
                     __HIP_MEMORY_SCOPE_SYSTEM);
}
__device__ __forceinline__ void st4_sc(unsigned* p, unsigned v){
  __hip_atomic_store(p, v, __ATOMIC_RELAXED, __HIP_MEMORY_SCOPE_SYSTEM);
}
__device__ __forceinline__ u32x4 ld16_sc(const unsigned* p){
  u32x4 r;
  asm volatile("global_load_dwordx4 %0, %1, off sc0 sc1\n\t"
               "s_waitcnt vmcnt(0)"
               : "=v"(r) : "v"(p) : "memory");
  return r;
}

// ---- batched MALL loads: 32 x global_load_dwordx4 sc0 sc1 from one row base ----
// Row layout: [row][1024] ushort, row = hi[0..511] ++ lo[0..511]; fragments at
// imm offsets 0..1984 of (row base + lk).
#define G16(i, ofs) "global_load_dwordx4 %" #i ", %16, off offset:" #ofs " sc0 sc1\n\t"
__device__ __forceinline__ void ld_row_batch(const unsigned short* p,
                                             bf16x8* A, bf16x8* B){
  asm volatile(
    G16(0,0)    G16(1,64)   G16(2,128)  G16(3,192)
    G16(4,256)  G16(5,320)  G16(6,384)  G16(7,448)
    G16(8,512)  G16(9,576)  G16(10,640) G16(11,704)
    G16(12,768) G16(13,832) G16(14,896) G16(15,960)
    : "=&v"(A[0]),"=&v"(A[1]),"=&v"(A[2]),"=&v"(A[3]),
      "=&v"(A[4]),"=&v"(A[5]),"=&v"(A[6]),"=&v"(A[7]),
      "=&v"(A[8]),"=&v"(A[9]),"=&v"(A[10]),"=&v"(A[11]),
      "=&v"(A[12]),"=&v"(A[13]),"=&v"(A[14]),"=&v"(A[15])
    : "v"(p));
  asm volatile(
    G16(0,1024) G16(1,1088) G16(2,1152) G16(3,1216)
    G16(4,1280) G16(5,1344) G16(6,1408) G16(7,1472)
    G16(8,1536) G16(9,1600) G16(10,1664) G16(11,1728)
    G16(12,1792) G16(13,1856) G16(14,1920) G16(15,1984)
    : "=&v"(B[0]),"=&v"(B[1]),"=&v"(B[2]),"=&v"(B[3]),
      "=&v"(B[4]),"=&v"(B[5]),"=&v"(B[6]),"=&v"(B[7]),
      "=&v"(B[8]),"=&v"(B[9]),"=&v"(B[10]),"=&v"(B[11]),
      "=&v"(B[12]),"=&v"(B[13]),"=&v"(B[14]),"=&v"(B[15])
    : "v"(p));
}

// ---- x fp32 [T,B,300] -> bf16 hi/lo planes [T,B,320] ----
__global__ __launch_bounds__(256) void prep_x(const float* __restrict__ x,
                                              unsigned short* __restrict__ xh,
                                              unsigned short* __restrict__ xl){
  long long n = (long long)T_STEPS * BATCH * KP;
  for (long long i = (long long)blockIdx.x * blockDim.x + threadIdx.x; i < n;
       i += (long long)gridDim.x * blockDim.x){
    int k = (int)(i % KP);
    long long tb = i / KP;
    float v = (k < IND) ? x[tb * IND + k] : 0.0f;
    unsigned short h = f2bf(v);
    xh[i] = h;
    xl[i] = f2bf(v - bf2f(h));
  }
}

// ---- one-shot W_ioux/W_fx fp32 -> bf16 hi/lo [1536][320] ----
__global__ __launch_bounds__(256) void prep_w(const float* __restrict__ Wioux,
                                              const float* __restrict__ Wfx,
                                              unsigned short* __restrict__ wxh,
                                              unsigned short* __restrict__ wxl){
  int n = 1536 * KP;
  for (int i = blockIdx.x * blockDim.x + threadIdx.x; i < n;
       i += gridDim.x * blockDim.x){
    int k = i % KP, row = i / KP;
    float v = 0.0f;
    if (k < IND) v = (row < 1024) ? Wioux[row*IND + k] : Wfx[(row-1024)*IND + k];
    unsigned short h = f2bf(v);
    wxh[i] = h;
    wxl[i] = f2bf(v - bf2f(h));
  }
}

// ---- P_iou[t][o][b] = x_t[b,:]·W_ioux[o,:] + b_ioux[o] + b_iouh[o] ----
__global__ __launch_bounds__(256) void proj_iou(const unsigned short* __restrict__ xh,
                                                const unsigned short* __restrict__ xl,
                                                const unsigned short* __restrict__ wxh,
                                                const unsigned short* __restrict__ wxl,
                                                const float* __restrict__ bx,
                                                const float* __restrict__ bh,
                                                float* __restrict__ P){
  const int t = blockIdx.x, obase = blockIdx.y * 64;
  __shared__ unsigned short wh[64*328];
  __shared__ unsigned short wl[64*328];
  for (int c = threadIdx.x; c < 64*40; c += 256){
    int r = c / 40, c8 = (c % 40) * 8;
    *(bf16x8*)(wh + r*328 + c8) = *(const bf16x8*)(wxh + (obase + r)*KP + c8);
    *(bf16x8*)(wl + r*328 + c8) = *(const bf16x8*)(wxl + (obase + r)*KP + c8);
  }
  __syncthreads();
  const int lane = threadIdx.x & 63, w = threadIdx.x >> 6;
  const int l15 = lane & 15, lk = (lane >> 4) << 3, lr4 = (lane >> 4) << 2;
  f32x4 acc[2][4] = {};
  const unsigned short* xbh = xh + (long long)t * BATCH * KP;
  const unsigned short* xbl = xl + (long long)t * BATCH * KP;
  for (int ks = 0; ks < 10; ++ks){
    int k0 = ks*32 + lk;
    bf16x8 ah[2], al[2];
    #pragma unroll
    for (int mt = 0; mt < 2; ++mt){
      int b = w*32 + mt*16 + l15;
      ah[mt] = *(const bf16x8*)(xbh + b*KP + k0);
      al[mt] = *(const bf16x8*)(xbl + b*KP + k0);
    }
    #pragma unroll
    for (int nt = 0; nt < 4; ++nt){
      bf16x8 bh8 = *(const bf16x8*)(wh + (nt*16 + l15)*328 + k0);
      bf16x8 bl8 = *(const bf16x8*)(wl + (nt*16 + l15)*328 + k0);
      #pragma unroll
      for (int mt = 0; mt < 2; ++mt){
        acc[mt][nt] = mfma16(ah[mt], bh8, acc[mt][nt]);
        acc[mt][nt] = mfma16(ah[mt], bl8, acc[mt][nt]);
        acc[mt][nt] = mfma16(al[mt], bh8, acc[mt][nt]);
      }
    }
  }
  #pragma unroll
  for (int nt = 0; nt < 4; ++nt){
    int o = obase + nt*16 + l15;
    float bias = bx[o] + bh[o];
    #pragma unroll
    for (int mt = 0; mt < 2; ++mt){
      int b0 = w*32 + mt*16 + lr4;
      *(f32x4*)(P + ((long long)t*1024 + o)*BATCH + b0) = acc[mt][nt] + bias;
    }
  }
}

// ---- P_f[t][b][m] = x_t[b,:]·W_fx[m,:] + b_fx[m] + b_Uh[m] ----
__global__ __launch_bounds__(256) void proj_f(const unsigned short* __restrict__ xh,
                                              const unsigned short* __restrict__ xl,
                                              const unsigned short* __restrict__ wxh,
                                              const unsigned short* __restrict__ wxl,
                                              const float* __restrict__ bf,
                                              const float* __restrict__ bu,
                                              float* __restrict__ Pf){
  const int t = blockIdx.x, mbase = blockIdx.y * 64;
  __shared__ unsigned short wh[64*328];
  __shared__ unsigned short wl[64*328];
  for (int c = threadIdx.x; c < 64*40; c += 256){
    int r = c / 40, c8 = (c % 40) * 8;
    *(bf16x8*)(wh + r*328 + c8) = *(const bf16x8*)(wxh + (1024 + mbase + r)*KP + c8);
    *(bf16x8*)(wl + r*328 + c8) = *(const bf16x8*)(wxl + (1024 + mbase + r)*KP + c8);
  }
  __syncthreads();
  const int lane = threadIdx.x & 63, w = threadIdx.x >> 6;
  const int l15 = lane & 15, lk = (lane >> 4) << 3, lr4 = (lane >> 4) << 2;
  f32x4 acc[4][2] = {};
  const unsigned short* xbh = xh + (long long)t * BATCH * KP;
  const unsigned short* xbl = xl + (long long)t * BATCH * KP;
  for (int ks = 0; ks < 10; ++ks){
    int k0 = ks*32 + lk;
    bf16x8 bh8[2], bl8[2];
    #pragma unroll
    for (int nt = 0; nt < 2; ++nt){
      int b = w*32 + nt*16 + l15;
      bh8[nt] = *(const bf16x8*)(xbh + b*KP + k0);
      bl8[nt] = *(const bf16x8*)(xbl + b*KP + k0);
    }
    #pragma unroll
    for (int mt = 0; mt < 4; ++mt){
      bf16x8 ah = *(const bf16x8*)(wh + (mt*16 + l15)*328 + k0);
      bf16x8 al = *(const bf16x8*)(wl + (mt*16 + l15)*328 + k0);
      #pragma unroll
      for (int nt = 0; nt < 2; ++nt){
        acc[mt][nt] = mfma16(ah, bh8[nt], acc[mt][nt]);
        acc[mt][nt] = mfma16(ah, bl8[nt], acc[mt][nt]);
        acc[mt][nt] = mfma16(al, bh8[nt], acc[mt][nt]);
      }
    }
  }
  #pragma unroll
  for (int mt = 0; mt < 4; ++mt){
    int m0 = mbase + mt*16 + lr4;
    f32x4 bias = *(const f32x4*)(bf + m0);
    f32x4 bias2 = *(const f32x4*)(bu + m0);
    #pragma unroll
    for (int nt = 0; nt < 2; ++nt){
      int b = w*32 + nt*16 + l15;
      *(f32x4*)(Pf + ((long long)t*BATCH + b)*MEM + m0) = acc[mt][nt] + bias + bias2;
    }
  }
}

// ---- persistent GRU scan: 256 WGs x 64 threads (1 wave each, 1/CU) ----
// 2-D tiling: WG(gb,gc) owns batch rows R..R+16 and cols C..C+16 of z/r/u.
// Weights (16z+16r+16u rows) LDS-resident; per phase each WG reads only its
// 16 h-rows (32 KB) over the sc-path -> 8x fewer bytes/CU than round 4.
__global__ __launch_bounds__(64, 1) void scan_kernel(
    const float* __restrict__ Wiouh, const float* __restrict__ Wuh,
    const float* __restrict__ Piou, const float* __restrict__ Pf,
    unsigned short* __restrict__ h2, unsigned short* __restrict__ rh2,
    float* __restrict__ out, unsigned* __restrict__ slots)
{
  const int gb = blockIdx.x >> 5;      // 0..7 batch group
  const int gc = blockIdx.x & 31;      // 0..31 col group
  const int R = gb * 16;               // batch row base
  const int C = gc * 16;               // col base
  const int lane = threadIdx.x;
  const int l15 = lane & 15, lk = (lane >> 4) << 3, lr4 = (lane >> 4) << 2;

  __shared__ unsigned short zr_h[32*520];   // rows 0-15: W_iouh z cols C..C+16; 16-31: r
  __shared__ unsigned short zr_l[32*520];
  __shared__ unsigned short wu_h[16*520];   // W_Uh cols C..C+16
  __shared__ unsigned short wu_l[16*520];
  __shared__ float          z_lds[16*20];   // [batch][col], stride 20 (16B-aligned rows)
  __shared__ float          hn_lds[16*20];  // own h tile fp32 [batch][col]
  __shared__ unsigned short fl_h[16*16];    // rh staging [batch][col]
  __shared__ unsigned short fl_l[16*16];

  for (int idx = lane; idx < 32*512; idx += 64){
    int r = idx >> 9, k = idx & 511;
    float vz = (r < 16) ? Wiouh[(C + r)*512 + k]
                        : Wiouh[(512 + C + (r - 16))*512 + k];
    unsigned short hz = f2bf(vz);
    zr_h[r*520 + k] = hz;
    zr_l[r*520 + k] = f2bf(vz - bf2f(hz));
    if (r < 16){
      float vu = Wuh[(C + r)*512 + k];
      unsigned short hu = f2bf(vu);
      wu_h[r*520 + k] = hu;
      wu_l[r*520 + k] = f2bf(vu - bf2f(hu));
    }
  }
  for (int idx = lane; idx < 16*20; idx += 64) hn_lds[idx] = 0.0f;
  __syncthreads();

  const unsigned short* ph = h2  + (R + l15)*1024 + lk;
  const unsigned short* pr = rh2 + (R + l15)*1024 + lk;
  unsigned gen = 0;

  f32x4 p1z = *(const f32x4*)(Piou + (long long)(C + l15)*BATCH + R + lr4);       // t=0
  f32x4 p1r = *(const f32x4*)(Piou + (long long)(512 + C + l15)*BATCH + R + lr4);

  for (int t = 0; t < T_STEPS; ++t){
    // ===== phase 1: z,r = sigmoid(h @ Wzr^T + P) ; rh = r*h =====
    {
      bf16x8 Ah[16], Al[16];
      __builtin_amdgcn_sched_barrier(0);
      ld_row_batch(ph, Ah, Al);
      asm volatile("s_waitcnt vmcnt(0)" ::: "memory");
      __builtin_amdgcn_sched_barrier(0);
      f32x4 az0 = {0.f,0.f,0.f,0.f}, az1 = {0.f,0.f,0.f,0.f};
      f32x4 ar0 = {0.f,0.f,0.f,0.f}, ar1 = {0.f,0.f,0.f,0.f};
      #pragma unroll
      for (int ks = 0; ks < 16; ks += 2){
        int k0 = ks*32 + lk, k1 = k0 + 32;
        bf16x8 zh0 = *(const bf16x8*)(zr_h + l15*520 + k0);
        bf16x8 zl0 = *(const bf16x8*)(zr_l + l15*520 + k0);
        bf16x8 rh0 = *(const bf16x8*)(zr_h + (16 + l15)*520 + k0);
        bf16x8 rl0 = *(const bf16x8*)(zr_l + (16 + l15)*520 + k0);
        az0 = mfma16(Ah[ks], zh0, az0);
        az0 = mfma16(Ah[ks], zl0, az0);
        az0 = mfma16(Al[ks], zh0, az0);
        ar0 = mfma16(Ah[ks], rh0, ar0);
        ar0 = mfma16(Ah[ks], rl0, ar0);
        ar0 = mfma16(Al[ks], rh0, ar0);
        bf16x8 zh1 = *(const bf16x8*)(zr_h + l15*520 + k1);
        bf16x8 zl1 = *(const bf16x8*)(zr_l + l15*520 + k1);
        bf16x8 rh1 = *(const bf16x8*)(zr_h + (16 + l15)*520 + k1);
        bf16x8 rl1 = *(const bf16x8*)(zr_l + (16 + l15)*520 + k1);
        az1 = mfma16(Ah[ks+1], zh1, az1);
        az1 = mfma16(Ah[ks+1], zl1, az1);
        az1 = mfma16(Al[ks+1], zh1, az1);
        ar1 = mfma16(Ah[ks+1], rh1, ar1);
        ar1 = mfma16(Ah[ks+1], rl1, ar1);
        ar1 = mfma16(Al[ks+1], rh1, ar1);
      }
      f32x4 az = az0 + az1, ar = ar0 + ar1;
      #pragma unroll
      for (int j = 0; j < 4; ++j){
        float zv = sigm(az[j] + p1z[j]);
        z_lds[(lr4 + j)*20 + l15] = zv;              // [batch][col]
        float rv = sigm(ar[j] + p1r[j]);
        float rh = rv * hn_lds[(lr4 + j)*20 + l15];  // fp32-exact own h
        unsigned short hi = f2bf(rh);
        fl_h[(lr4 + j)*16 + l15] = hi;
        fl_l[(lr4 + j)*16 + l15] = f2bf(rh - bf2f(hi));
      }
    }
    asm volatile("s_waitcnt lgkmcnt(0)" ::: "memory");
    __builtin_amdgcn_sched_barrier(0);
    { // flush rh tile: 16 rows x (16+16 B), 2 x 8B sc stores per lane
      int row = lane >> 2, c4 = (lane & 3) * 4;
      st8_sc(rh2 + (R + row)*1024 + C + c4,
             *(const unsigned long long*)(fl_h + row*16 + c4));
      st8_sc(rh2 + (R + row)*1024 + 512 + C + c4,
             *(const unsigned long long*)(fl_l + row*16 + c4));
    }
    asm volatile("s_waitcnt vmcnt(0)" ::: "memory");
    ++gen;
    if (lane == 0) st4_sc(&slots[blockIdx.x], gen);
    f32x4 p2 = *(const f32x4*)(Pf + ((long long)t*BATCH + R + l15)*MEM + C + lr4);
    for (;;){
      u32x4 v = ld16_sc(slots + lane*4);
      if (__all(v[0] >= gen && v[1] >= gen && v[2] >= gen && v[3] >= gen)) break;
      __builtin_amdgcn_s_sleep(2);
    }
    asm volatile("" ::: "memory");

    // ===== phase 2: u = tanh(rh @ Wu^T + Pf); h = (1-z)h + z*u =====
    {
      bf16x8 Bh[16], Bl[16];
      __builtin_amdgcn_sched_barrier(0);
      ld_row_batch(pr, Bh, Bl);
      asm volatile("s_waitcnt vmcnt(0)" ::: "memory");
      __builtin_amdgcn_sched_barrier(0);
      f32x4 au0 = {0.f,0.f,0.f,0.f}, au1 = {0.f,0.f,0.f,0.f};
      #pragma unroll
      for (int ks = 0; ks < 16; ks += 2){
        int k0 = ks*32 + lk, k1 = k0 + 32;
        bf16x8 a_h0 = *(const bf16x8*)(wu_h + l15*520 + k0);
        bf16x8 a_l0 = *(const bf16x8*)(wu_l + l15*520 + k0);
        au0 = mfma16(a_h0, Bh[ks], au0);
        au0 = mfma16(a_h0, Bl[ks], au0);
        au0 = mfma16(a_l0, Bh[ks], au0);
        bf16x8 a_h1 = *(const bf16x8*)(wu_h + l15*520 + k1);
        bf16x8 a_l1 = *(const bf16x8*)(wu_l + l15*520 + k1);
        au1 = mfma16(a_h1, Bh[ks+1], au1);
        au1 = mfma16(a_h1, Bl[ks+1], au1);
        au1 = mfma16(a_l1, Bh[ks+1], au1);
      }
      f32x4 au = au0 + au1;
      // lane: batch = R + l15 (B-rows), cols m = C + lr4 + j (A-rows)
      f32x4 zz   = *(const f32x4*)(&z_lds[l15*20 + lr4]);
      f32x4 hold = *(const f32x4*)(&hn_lds[l15*20 + lr4]);
      f32x4 hn;
      u16x4 nh, nl;
      #pragma unroll
      for (int j = 0; j < 4; ++j){
        float ht = tanh_(au[j] + p2[j]);
        float hv = (1.0f - zz[j])*hold[j] + zz[j]*ht;
        hn[j] = hv;
        unsigned short nhi = f2bf(hv);
        nh[j] = nhi;
        nl[j] = f2bf(hv - bf2f(nhi));
      }
      *(f32x4*)(&hn_lds[l15*20 + lr4]) = hn;
      *(f32x4*)(out + ((long long)t*BATCH + R + l15)*MEM + C + lr4) = hn; // plain
      union { u16x4 s; unsigned long long q; } uh, ul;
      uh.s = nh; ul.s = nl;
      st8_sc(h2 + (R + l15)*1024 + C + lr4, uh.q);          // hi plane
      st8_sc(h2 + (R + l15)*1024 + 512 + C + lr4, ul.q);    // lo plane
    }
    asm volatile("s_waitcnt vmcnt(0)" ::: "memory");
    ++gen;
    if (lane == 0) st4_sc(&slots[blockIdx.x], gen);
    if (t + 1 < T_STEPS){
      p1z = *(const f32x4*)(Piou + ((long long)(t+1)*1024 + C + l15)*BATCH + R + lr4);
      p1r = *(const f32x4*)(Piou + ((long long)(t+1)*1024 + 512 + C + l15)*BATCH + R + lr4);
    }
    for (;;){
      u32x4 v = ld16_sc(slots + lane*4);
      if (__all(v[0] >= gen && v[1] >= gen && v[2] >= gen && v[3] >= gen)) break;
      __builtin_amdgcn_s_sleep(2);
    }
    asm volatile("" ::: "memory");
  }
}

extern "C" void kernel_launch(void* const* d_in, const int* in_sizes, int n_in,
                              void* d_out, int out_size, void* d_ws, size_t ws_size,
                              hipStream_t stream){
  (void)in_sizes; (void)n_in; (void)out_size; (void)ws_size;
  const float* x     = (const float*)d_in[0];
  const float* Wioux = (const float*)d_in[1];
  const float* bioux = (const float*)d_in[2];
  const float* Wiouh = (const float*)d_in[3];
  const float* biouh = (const float*)d_in[4];
  const float* Wfx   = (const float*)d_in[5];
  const float* bfx   = (const float*)d_in[6];
  const float* Wuh   = (const float*)d_in[7];
  const float* buh   = (const float*)d_in[8];
  float* out = (float*)d_out;

  char* ws = (char*)d_ws;
  size_t off = 0;
  auto alloc = [&](size_t bytes) -> void* {
    void* p = ws + off;
    off += (bytes + 255) & ~(size_t)255;
    return p;
  };
  float* Piou = (float*)alloc((size_t)T_STEPS*1024*BATCH*sizeof(float)); // 268 MB
  float* Pf   = (float*)alloc((size_t)T_STEPS*BATCH*MEM*sizeof(float));  // 134 MB
  unsigned short* xh = (unsigned short*)alloc((size_t)T_STEPS*BATCH*KP*2);
  unsigned short* xl = (unsigned short*)alloc((size_t)T_STEPS*BATCH*KP*2);
  unsigned short* wxh = (unsigned short*)alloc((size_t)1536*KP*2);
  unsigned short* wxl = (unsigned short*)alloc((size_t)1536*KP*2);
  unsigned short* h2  = (unsigned short*)alloc((size_t)BATCH*1024*2);
  unsigned short* rh2 = (unsigned short*)alloc((size_t)BATCH*1024*2);
  unsigned* slots = (unsigned*)alloc(NWG*4);

  hipMemsetAsync(h2, 0, (size_t)BATCH*1024*2, stream);   // h0 = 0
  hipMemsetAsync(slots, 0, NWG*4, stream);               // barrier slots

  prep_x<<<2048, 256, 0, stream>>>(x, xh, xl);
  prep_w<<<512, 256, 0, stream>>>(Wioux, Wfx, wxh, wxl);
  proj_iou<<<dim3(T_STEPS, 16), 256, 0, stream>>>(xh, xl, wxh, wxl, bioux, biouh, Piou);
  proj_f<<<dim3(T_STEPS, 8), 256, 0, stream>>>(xh, xl, wxh, wxl, bfx, buh, Pf);
  scan_kernel<<<NWG, 64, 0, stream>>>(Wiouh, Wuh, Piou, Pf, h2, rh2, out, slots);
}

// Round 8
// 4437.651 us; speedup vs baseline: 3.2646x; 1.5023x over previous
//
#include <hip/hip_runtime.h>

#define T_STEPS 512
#define BATCH   128
#define IND     300
#define KP      320   // K padded to 10*32 for MFMA
#define MEM     512
#define NWG     256   // 8 batch-groups x 32 col-groups, 1 wave each

typedef short bf16x8 __attribute__((ext_vector_type(8)));
typedef float f32x4  __attribute__((ext_vector_type(4)));
typedef unsigned short u16x4 __attribute__((ext_vector_type(4)));

__device__ __forceinline__ unsigned short f2bf(float f){
  unsigned u = __float_as_uint(f);
  u += 0x7FFFu + ((u >> 16) & 1u);           // RNE
  return (unsigned short)(u >> 16);
}
__device__ __forceinline__ float bf2f(unsigned short s){
  return __uint_as_float(((unsigned)s) << 16);
}
__device__ __forceinline__ f32x4 mfma16(bf16x8 a, bf16x8 b, f32x4 c){
  return __builtin_amdgcn_mfma_f32_16x16x32_bf16(a, b, c, 0, 0, 0);
}
__device__ __forceinline__ float sigm(float x){ return 1.0f/(1.0f + __expf(-x)); }
__device__ __forceinline__ float tanh_(float x){
  float t = __expf(-2.0f * fabsf(x));
  float r = (1.0f - t)/(1.0f + t);
  return x < 0.0f ? -r : r;
}

// ---- MALL-coherent (uncached sc0 sc1) scalar ops — verified rounds 2/4/7 ----
__device__ __forceinline__ void st8_sc(void* p, unsigned long long v){
  __hip_atomic_store((unsigned long long*)p, v, __ATOMIC_RELAXED,
                     __HIP_MEMORY_SCOPE_SYSTEM);
}
__device__ __forceinline__ void st4_sc(unsigned* p, unsigned v){
  __hip_atomic_store(p, v, __ATOMIC_RELAXED, __HIP_MEMORY_SCOPE_SYSTEM);
}
__device__ __forceinline__ unsigned ld4_sc(const unsigned* p){
  return __hip_atomic_load(p, __ATOMIC_RELAXED, __HIP_MEMORY_SCOPE_SYSTEM);
}

// ---- flat contiguous uncached loads: 4 x dwordx4, each wave-instr = 1 KB
// contiguous = 8 full 128B MALL lines (vs 16 scattered partial-line requests) ----
#define FLAT4(D0,D1,D2,D3,PTR) \
  asm volatile( \
    "global_load_dwordx4 %0, %4, off sc0 sc1\n\t" \
    "global_load_dwordx4 %1, %4, off offset:1024 sc0 sc1\n\t" \
    "global_load_dwordx4 %2, %4, off offset:2048 sc0 sc1\n\t" \
    "global_load_dwordx4 %3, %4, off offset:3072 sc0 sc1\n\t" \
    : "=&v"(D0),"=&v"(D1),"=&v"(D2),"=&v"(D3) : "v"(PTR))

// ---- x fp32 [T,B,300] -> bf16 hi/lo planes [T,B,320] ----
__global__ __launch_bounds__(256) void prep_x(const float* __restrict__ x,
                                              unsigned short* __restrict__ xh,
                                              unsigned short* __restrict__ xl){
  long long n = (long long)T_STEPS * BATCH * KP;
  for (long long i = (long long)blockIdx.x * blockDim.x + threadIdx.x; i < n;
       i += (long long)gridDim.x * blockDim.x){
    int k = (int)(i % KP);
    long long tb = i / KP;
    float v = (k < IND) ? x[tb * IND + k] : 0.0f;
    unsigned short h = f2bf(v);
    xh[i] = h;
    xl[i] = f2bf(v - bf2f(h));
  }
}

// ---- one-shot W_ioux/W_fx fp32 -> bf16 hi/lo [1536][320] ----
__global__ __launch_bounds__(256) void prep_w(const float* __restrict__ Wioux,
                                              const float* __restrict__ Wfx,
                                              unsigned short* __restrict__ wxh,
                                              unsigned short* __restrict__ wxl){
  int n = 1536 * KP;
  for (int i = blockIdx.x * blockDim.x + threadIdx.x; i < n;
       i += gridDim.x * blockDim.x){
    int k = i % KP, row = i / KP;
    float v = 0.0f;
    if (k < IND) v = (row < 1024) ? Wioux[row*IND + k] : Wfx[(row-1024)*IND + k];
    unsigned short h = f2bf(v);
    wxh[i] = h;
    wxl[i] = f2bf(v - bf2f(h));
  }
}

// ---- P_iou[t][o][b] = x_t[b,:]·W_ioux[o,:] + b_ioux[o] + b_iouh[o] ----
__global__ __launch_bounds__(256) void proj_iou(const unsigned short* __restrict__ xh,
                                                const unsigned short* __restrict__ xl,
                                                const unsigned short* __restrict__ wxh,
                                                const unsigned short* __restrict__ wxl,
                                                const float* __restrict__ bx,
                                                const float* __restrict__ bh,
                                                float* __restrict__ P){
  const int t = blockIdx.x, obase = blockIdx.y * 64;
  __shared__ unsigned short wh[64*328];
  __shared__ unsigned short wl[64*328];
  for (int c = threadIdx.x; c < 64*40; c += 256){
    int r = c / 40, c8 = (c % 40) * 8;
    *(bf16x8*)(wh + r*328 + c8) = *(const bf16x8*)(wxh + (obase + r)*KP + c8);
    *(bf16x8*)(wl + r*328 + c8) = *(const bf16x8*)(wxl + (obase + r)*KP + c8);
  }
  __syncthreads();
  const int lane = threadIdx.x & 63, w = threadIdx.x >> 6;
  const int l15 = lane & 15, lk = (lane >> 4) << 3, lr4 = (lane >> 4) << 2;
  f32x4 acc[2][4] = {};
  const unsigned short* xbh = xh + (long long)t * BATCH * KP;
  const unsigned short* xbl = xl + (long long)t * BATCH * KP;
  for (int ks = 0; ks < 10; ++ks){
    int k0 = ks*32 + lk;
    bf16x8 ah[2], al[2];
    #pragma unroll
    for (int mt = 0; mt < 2; ++mt){
      int b = w*32 + mt*16 + l15;
      ah[mt] = *(const bf16x8*)(xbh + b*KP + k0);
      al[mt] = *(const bf16x8*)(xbl + b*KP + k0);
    }
    #pragma unroll
    for (int nt = 0; nt < 4; ++nt){
      bf16x8 bh8 = *(const bf16x8*)(wh + (nt*16 + l15)*328 + k0);
      bf16x8 bl8 = *(const bf16x8*)(wl + (nt*16 + l15)*328 + k0);
      #pragma unroll
      for (int mt = 0; mt < 2; ++mt){
        acc[mt][nt] = mfma16(ah[mt], bh8, acc[mt][nt]);
        acc[mt][nt] = mfma16(ah[mt], bl8, acc[mt][nt]);
        acc[mt][nt] = mfma16(al[mt], bh8, acc[mt][nt]);
      }
    }
  }
  #pragma unroll
  for (int nt = 0; nt < 4; ++nt){
    int o = obase + nt*16 + l15;
    float bias = bx[o] + bh[o];
    #pragma unroll
    for (int mt = 0; mt < 2; ++mt){
      int b0 = w*32 + mt*16 + lr4;
      *(f32x4*)(P + ((long long)t*1024 + o)*BATCH + b0) = acc[mt][nt] + bias;
    }
  }
}

// ---- P_f[t][b][m] = x_t[b,:]·W_fx[m,:] + b_fx[m] + b_Uh[m] ----
__global__ __launch_bounds__(256) void proj_f(const unsigned short* __restrict__ xh,
                                              const unsigned short* __restrict__ xl,
                                              const unsigned short* __restrict__ wxh,
                                              const unsigned short* __restrict__ wxl,
                                              const float* __restrict__ bf,
                                              const float* __restrict__ bu,
                                              float* __restrict__ Pf){
  const int t = blockIdx.x, mbase = blockIdx.y * 64;
  __shared__ unsigned short wh[64*328];
  __shared__ unsigned short wl[64*328];
  for (int c = threadIdx.x; c < 64*40; c += 256){
    int r = c / 40, c8 = (c % 40) * 8;
    *(bf16x8*)(wh + r*328 + c8) = *(const bf16x8*)(wxh + (1024 + mbase + r)*KP + c8);
    *(bf16x8*)(wl + r*328 + c8) = *(const bf16x8*)(wxl + (1024 + mbase + r)*KP + c8);
  }
  __syncthreads();
  const int lane = threadIdx.x & 63, w = threadIdx.x >> 6;
  const int l15 = lane & 15, lk = (lane >> 4) << 3, lr4 = (lane >> 4) << 2;
  f32x4 acc[4][2] = {};
  const unsigned short* xbh = xh + (long long)t * BATCH * KP;
  const unsigned short* xbl = xl + (long long)t * BATCH * KP;
  for (int ks = 0; ks < 10; ++ks){
    int k0 = ks*32 + lk;
    bf16x8 bh8[2], bl8[2];
    #pragma unroll
    for (int nt = 0; nt < 2; ++nt){
      int b = w*32 + nt*16 + l15;
      bh8[nt] = *(const bf16x8*)(xbh + b*KP + k0);
      bl8[nt] = *(const bf16x8*)(xbl + b*KP + k0);
    }
    #pragma unroll
    for (int mt = 0; mt < 4; ++mt){
      bf16x8 ah = *(const bf16x8*)(wh + (mt*16 + l15)*328 + k0);
      bf16x8 al = *(const bf16x8*)(wl + (mt*16 + l15)*328 + k0);
      #pragma unroll
      for (int nt = 0; nt < 2; ++nt){
        acc[mt][nt] = mfma16(ah, bh8[nt], acc[mt][nt]);
        acc[mt][nt] = mfma16(ah, bl8[nt], acc[mt][nt]);
        acc[mt][nt] = mfma16(al, bh8[nt], acc[mt][nt]);
      }
    }
  }
  #pragma unroll
  for (int mt = 0; mt < 4; ++mt){
    int m0 = mbase + mt*16 + lr4;
    f32x4 bias = *(const f32x4*)(bf + m0);
    f32x4 bias2 = *(const f32x4*)(bu + m0);
    #pragma unroll
    for (int nt = 0; nt < 2; ++nt){
      int b = w*32 + nt*16 + l15;
      *(f32x4*)(Pf + ((long long)t*BATCH + b)*MEM + m0) = acc[mt][nt] + bias + bias2;
    }
  }
}

// ---- persistent GRU scan: 256 WGs x 64 threads (1 wave each, 1/CU) ----
// WG(gb,gc): batch rows R..R+16, cols C..C+16. Data only flows WITHIN a
// batch-group -> 32-wide group-local barrier (1 cache line of slots).
// h broadcast: hi/lo bf16 [128][1024]; rh: SINGLE-plane bf16 [128][512].
// All cross-WG loads are flat-contiguous (full-line requests) + LDS redistribute.
__global__ __launch_bounds__(64, 1) void scan_kernel(
    const float* __restrict__ Wiouh, const float* __restrict__ Wuh,
    const float* __restrict__ Piou, const float* __restrict__ Pf,
    unsigned short* __restrict__ h2, unsigned short* __restrict__ rh2,
    float* __restrict__ out, unsigned* __restrict__ slots)
{
  const int gb = blockIdx.x >> 5;      // 0..7 batch group
  const int gc = blockIdx.x & 31;      // 0..31 col group
  const int R = gb * 16;               // batch row base
  const int C = gc * 16;               // col base
  const int lane = threadIdx.x;
  const int l15 = lane & 15, lk = (lane >> 4) << 3, lr4 = (lane >> 4) << 2;

  __shared__ unsigned short zr_h[32*520];   // rows 0-15: W_iouh z cols C..C+16; 16-31: r
  __shared__ unsigned short zr_l[32*520];
  __shared__ unsigned short wu_h[16*520];   // W_Uh cols C..C+16
  __shared__ unsigned short wu_l[16*520];
  __shared__ unsigned short stage[16*1032]; // flat-load staging (2064B-row pad, 2-way banks)
  __shared__ float          z_lds[16*20];   // [batch][col]
  __shared__ float          hn_lds[16*20];  // own h tile fp32 [batch][col]
  __shared__ unsigned short fl[16*16];      // rh staging (single plane)

  for (int idx = lane; idx < 32*512; idx += 64){
    int r = idx >> 9, k = idx & 511;
    float vz = (r < 16) ? Wiouh[(C + r)*512 + k]
                        : Wiouh[(512 + C + (r - 16))*512 + k];
    unsigned short hz = f2bf(vz);
    zr_h[r*520 + k] = hz;
    zr_l[r*520 + k] = f2bf(vz - bf2f(hz));
    if (r < 16){
      float vu = Wuh[(C + r)*512 + k];
      unsigned short hu = f2bf(vu);
      wu_h[r*520 + k] = hu;
      wu_l[r*520 + k] = f2bf(vu - bf2f(hu));
    }
  }
  for (int idx = lane; idx < 16*20; idx += 64) hn_lds[idx] = 0.0f;
  __syncthreads();

  unsigned* gslot = slots + gb*32;     // this group's 32 slots = one 128B line
  unsigned gen = 0;

  f32x4 p1z = *(const f32x4*)(Piou + (long long)(C + l15)*BATCH + R + lr4);       // t=0
  f32x4 p1r = *(const f32x4*)(Piou + (long long)(512 + C + l15)*BATCH + R + lr4);

  for (int t = 0; t < T_STEPS; ++t){
    // ===== phase 1: z,r = sigmoid(h @ Wzr^T + P) ; rh = r*h =====
    {
      // flat 32 KB read of h rows R..R+16 (hi+lo), full-line requests
      bf16x8 L[32];
      const unsigned short* hb = h2 + (size_t)R*1024 + lane*8;
      __builtin_amdgcn_sched_barrier(0);
      FLAT4(L[0],L[1],L[2],L[3],   hb);
      FLAT4(L[4],L[5],L[6],L[7],   hb + 2048);
      FLAT4(L[8],L[9],L[10],L[11], hb + 4096);
      FLAT4(L[12],L[13],L[14],L[15], hb + 6144);
      FLAT4(L[16],L[17],L[18],L[19], hb + 8192);
      FLAT4(L[20],L[21],L[22],L[23], hb + 10240);
      FLAT4(L[24],L[25],L[26],L[27], hb + 12288);
      FLAT4(L[28],L[29],L[30],L[31], hb + 14336);
      asm volatile("s_waitcnt vmcnt(0)" ::: "memory");
      __builtin_amdgcn_sched_barrier(0);
      #pragma unroll
      for (int i = 0; i < 32; ++i)
        *(bf16x8*)(stage + (i>>1)*1032 + (i&1)*512 + lane*8) = L[i];
      bf16x8 Ah[16], Al[16];
      #pragma unroll
      for (int ks = 0; ks < 16; ++ks){
        Ah[ks] = *(const bf16x8*)(stage + l15*1032 + ks*32 + lk);
        Al[ks] = *(const bf16x8*)(stage + l15*1032 + 512 + ks*32 + lk);
      }
      f32x4 az0 = {0.f,0.f,0.f,0.f}, az1 = {0.f,0.f,0.f,0.f};
      f32x4 ar0 = {0.f,0.f,0.f,0.f}, ar1 = {0.f,0.f,0.f,0.f};
      #pragma unroll
      for (int ks = 0; ks < 16; ks += 2){
        int k0 = ks*32 + lk, k1 = k0 + 32;
        bf16x8 zh0 = *(const bf16x8*)(zr_h + l15*520 + k0);
        bf16x8 zl0 = *(const bf16x8*)(zr_l + l15*520 + k0);
        bf16x8 rh0 = *(const bf16x8*)(zr_h + (16 + l15)*520 + k0);
        bf16x8 rl0 = *(const bf16x8*)(zr_l + (16 + l15)*520 + k0);
        az0 = mfma16(Ah[ks], zh0, az0);
        az0 = mfma16(Ah[ks], zl0, az0);
        az0 = mfma16(Al[ks], zh0, az0);
        ar0 = mfma16(Ah[ks], rh0, ar0);
        ar0 = mfma16(Ah[ks], rl0, ar0);
        ar0 = mfma16(Al[ks], rh0, ar0);
        bf16x8 zh1 = *(const bf16x8*)(zr_h + l15*520 + k1);
        bf16x8 zl1 = *(const bf16x8*)(zr_l + l15*520 + k1);
        bf16x8 rh1 = *(const bf16x8*)(zr_h + (16 + l15)*520 + k1);
        bf16x8 rl1 = *(const bf16x8*)(zr_l + (16 + l15)*520 + k1);
        az1 = mfma16(Ah[ks+1], zh1, az1);
        az1 = mfma16(Ah[ks+1], zl1, az1);
        az1 = mfma16(Al[ks+1], zh1, az1);
        ar1 = mfma16(Ah[ks+1], rh1, ar1);
        ar1 = mfma16(Ah[ks+1], rl1, ar1);
        ar1 = mfma16(Al[ks+1], rh1, ar1);
      }
      f32x4 az = az0 + az1, ar = ar0 + ar1;
      #pragma unroll
      for (int j = 0; j < 4; ++j){
        float zv = sigm(az[j] + p1z[j]);
        z_lds[(lr4 + j)*20 + l15] = zv;              // [batch][col]
        float rv = sigm(ar[j] + p1r[j]);
        float rhv = rv * hn_lds[(lr4 + j)*20 + l15]; // fp32-exact own h
        fl[(lr4 + j)*16 + l15] = f2bf(rhv);          // single-plane rh
      }
    }
    asm volatile("s_waitcnt lgkmcnt(0)" ::: "memory");
    __builtin_amdgcn_sched_barrier(0);
    { // flush rh tile: 16 rows x 32 B, one 8B sc store per lane
      int row = lane >> 2, c4 = (lane & 3) * 4;
      st8_sc(rh2 + (R + row)*512 + C + c4,
             *(const unsigned long long*)(fl + row*16 + c4));
    }
    asm volatile("s_waitcnt vmcnt(0)" ::: "memory");
    ++gen;
    if (lane == 0) st4_sc(&gslot[gc], gen);
    f32x4 p2 = *(const f32x4*)(Pf + ((long long)t*BATCH + R + l15)*MEM + C + lr4);
    for (;;){ // group-local barrier: one coalesced 128B line per poll
      unsigned v = ld4_sc(&gslot[lane & 31]);
      if (__all((int)(v >= gen))) break;
      __builtin_amdgcn_s_sleep(2);
    }
    asm volatile("" ::: "memory");

    // ===== phase 2: u = tanh(rh @ Wu^T + Pf); h = (1-z)h + z*u =====
    {
      bf16x8 Lr[16];
      const unsigned short* rb = rh2 + (size_t)R*512 + lane*8;
      __builtin_amdgcn_sched_barrier(0);
      FLAT4(Lr[0],Lr[1],Lr[2],Lr[3],    rb);
      FLAT4(Lr[4],Lr[5],Lr[6],Lr[7],    rb + 2048);
      FLAT4(Lr[8],Lr[9],Lr[10],Lr[11],  rb + 4096);
      FLAT4(Lr[12],Lr[13],Lr[14],Lr[15], rb + 6144);
      asm volatile("s_waitcnt vmcnt(0)" ::: "memory");
      __builtin_amdgcn_sched_barrier(0);
      #pragma unroll
      for (int i = 0; i < 16; ++i)
        *(bf16x8*)(stage + i*520 + lane*8) = Lr[i];
      bf16x8 Br[16];
      #pragma unroll
      for (int ks = 0; ks < 16; ++ks)
        Br[ks] = *(const bf16x8*)(stage + l15*520 + ks*32 + lk);
      f32x4 au0 = {0.f,0.f,0.f,0.f}, au1 = {0.f,0.f,0.f,0.f};
      #pragma unroll
      for (int ks = 0; ks < 16; ks += 2){
        int k0 = ks*32 + lk, k1 = k0 + 32;
        bf16x8 a_h0 = *(const bf16x8*)(wu_h + l15*520 + k0);
        bf16x8 a_l0 = *(const bf16x8*)(wu_l + l15*520 + k0);
        au0 = mfma16(a_h0, Br[ks], au0);
        au0 = mfma16(a_l0, Br[ks], au0);
        bf16x8 a_h1 = *(const bf16x8*)(wu_h + l15*520 + k1);
        bf16x8 a_l1 = *(const bf16x8*)(wu_l + l15*520 + k1);
        au1 = mfma16(a_h1, Br[ks+1], au1);
        au1 = mfma16(a_l1, Br[ks+1], au1);
      }
      f32x4 au = au0 + au1;
      // lane: batch = R + l15 (n), col m = C + lr4 + j (m)
      f32x4 zz   = *(const f32x4*)(&z_lds[l15*20 + lr4]);
      f32x4 hold = *(const f32x4*)(&hn_lds[l15*20 + lr4]);
      f32x4 hn;
      u16x4 nh, nl;
      #pragma unroll
      for (int j = 0; j < 4; ++j){
        float ht = tanh_(au[j] + p2[j]);
        float hv = (1.0f - zz[j])*hold[j] + zz[j]*ht;
        hn[j] = hv;
        unsigned short nhi = f2bf(hv);
        nh[j] = nhi;
        nl[j] = f2bf(hv - bf2f(nhi));
      }
      *(f32x4*)(&hn_lds[l15*20 + lr4]) = hn;
      *(f32x4*)(out + ((long long)t*BATCH + R + l15)*MEM + C + lr4) = hn; // plain
      union { u16x4 s; unsigned long long q; } uh, ul;
      uh.s = nh; ul.s = nl;
      st8_sc(h2 + (R + l15)*1024 + C + lr4, uh.q);          // hi plane
      st8_sc(h2 + (R + l15)*1024 + 512 + C + lr4, ul.q);    // lo plane
    }
    asm volatile("s_waitcnt vmcnt(0)" ::: "memory");
    ++gen;
    if (lane == 0) st4_sc(&gslot[gc], gen);
    if (t + 1 < T_STEPS){
      p1z = *(const f32x4*)(Piou + ((long long)(t+1)*1024 + C + l15)*BATCH + R + lr4);
      p1r = *(const f32x4*)(Piou + ((long long)(t+1)*1024 + 512 + C + l15)*BATCH + R + lr4);
    }
    for (;;){
      unsigned v = ld4_sc(&gslot[lane & 31]);
      if (__all((int)(v >= gen))) break;
      __builtin_amdgcn_s_sleep(2);
    }
    asm volatile("" ::: "memory");
  }
}

extern "C" void kernel_launch(void* const* d_in, const int* in_sizes, int n_in,
                              void* d_out, int out_size, void* d_ws, size_t ws_size,
                              hipStream_t stream){
  (void)in_sizes; (void)n_in; (void)out_size; (void)ws_size;
  const float* x     = (const float*)d_in[0];
  const float* Wioux = (const float*)d_in[1];
  const float* bioux = (const float*)d_in[2];
  const float* Wiouh = (const float*)d_in[3];
  const float* biouh = (const float*)d_in[4];
  const float* Wfx   = (const float*)d_in[5];
  const float* bfx   = (const float*)d_in[6];
  const float* Wuh   = (const float*)d_in[7];
  const float* buh   = (const float*)d_in[8];
  float* out = (float*)d_out;

  char* ws = (char*)d_ws;
  size_t off = 0;
  auto alloc = [&](size_t bytes) -> void* {
    void* p = ws + off;
    off += (bytes + 255) & ~(size_t)255;
    return p;
  };
  float* Piou = (float*)alloc((size_t)T_STEPS*1024*BATCH*sizeof(float)); // 268 MB
  float* Pf   = (float*)alloc((size_t)T_STEPS*BATCH*MEM*sizeof(float));  // 134 MB
  unsigned short* xh = (unsigned short*)alloc((size_t)T_STEPS*BATCH*KP*2);
  unsigned short* xl = (unsigned short*)alloc((size_t)T_STEPS*BATCH*KP*2);
  unsigned short* wxh = (unsigned short*)alloc((size_t)1536*KP*2);
  unsigned short* wxl = (unsigned short*)alloc((size_t)1536*KP*2);
  unsigned short* h2  = (unsigned short*)alloc((size_t)BATCH*1024*2);  // hi||lo
  unsigned short* rh2 = (unsigned short*)alloc((size_t)BATCH*512*2);   // single plane
  unsigned* slots = (unsigned*)alloc(1024);   // 8 groups x 32 slots (128B/group)

  hipMemsetAsync(h2, 0, (size_t)BATCH*1024*2, stream);   // h0 = 0
  hipMemsetAsync(slots, 0, 1024, stream);                // barrier slots

  prep_x<<<2048, 256, 0, stream>>>(x, xh, xl);
  prep_w<<<512, 256, 0, stream>>>(Wioux, Wfx, wxh, wxl);
  proj_iou<<<dim3(T_STEPS, 16), 256, 0, stream>>>(xh, xl, wxh, wxl, bioux, biouh, Piou);
  proj_f<<<dim3(T_STEPS, 8), 256, 0, stream>>>(xh, xl, wxh, wxl, bfx, buh, Pf);
  scan_kernel<<<NWG, 64, 0, stream>>>(Wiouh, Wuh, Piou, Pf, h2, rh2, out, slots);
}